// Round 5
// baseline (180.537 us; speedup 1.0000x reference)
//
#include <hip/hip_runtime.h>
#include <hip/hip_bf16.h>

typedef __attribute__((ext_vector_type(8))) int   i32x8;   // 32 B = fp8 MFMA A/B operand (8 VGPRs)
typedef __attribute__((ext_vector_type(4))) int   i32x4;
typedef __attribute__((ext_vector_type(4))) float f32x4;   // MFMA C/D

constexpr int BB = 4096;   // batch B
constexpr int D  = 256;    // feature dim
constexpr int R2 = 8192;   // 2B rows of z
constexpr int NSPLIT = 32; // column splits (256 cols per block)
constexpr int CT = 64;     // columns staged per LDS tile
constexpr int NT = (R2 / NSPLIT) / CT;  // 4 tiles per block
constexpr float SQRT2 = 1.41421356237309515f;
constexpr float E2 = 7.38905609893065f;  // exp(2) == exp(diag sim)

// Async 16B/lane global->LDS DMA. Dest is wave-uniform base + lane*16 (HW-fixed).
__device__ __forceinline__ void async16(const unsigned char* g, unsigned char* l) {
    __builtin_amdgcn_global_load_lds(
        (const __attribute__((address_space(1))) void*)g,
        (__attribute__((address_space(3))) void*)l,
        16, 0, 0);
}

// Kernel A: L2-normalize rows, scale by sqrt(2), store fp8-e4m3 z[8192][256];
// pos[k] = 2*cos(xi_k, xj_k) in fp32. One wave per pair k. Also zero-inits out[0]
// (stream-ordered before reduce_kernel's atomics).
__global__ __launch_bounds__(256) void norm_kernel(const float* __restrict__ xi,
                                                   const float* __restrict__ xj,
                                                   int* __restrict__ z8,
                                                   float* __restrict__ pos,
                                                   float* __restrict__ out) {
    const int wid = threadIdx.x >> 6, lane = threadIdx.x & 63;
    const int k = blockIdx.x * 4 + wid;
    if (blockIdx.x == 0 && threadIdx.x == 0) out[0] = 0.f;
    const float4* a4 = reinterpret_cast<const float4*>(xi + (size_t)k * D);
    const float4* b4 = reinterpret_cast<const float4*>(xj + (size_t)k * D);
    float4 a = a4[lane], b = b4[lane];
    float ssi = a.x*a.x + a.y*a.y + a.z*a.z + a.w*a.w;
    float ssj = b.x*b.x + b.y*b.y + b.z*b.z + b.w*b.w;
    float dot = a.x*b.x + a.y*b.y + a.z*b.z + a.w*b.w;
#pragma unroll
    for (int off = 32; off; off >>= 1) {
        ssi += __shfl_xor(ssi, off);
        ssj += __shfl_xor(ssj, off);
        dot += __shfl_xor(dot, off);
    }
    const float inv_i = 1.0f / fmaxf(sqrtf(ssi), 1e-12f);
    const float inv_j = 1.0f / fmaxf(sqrtf(ssj), 1e-12f);
    const float si = inv_i * SQRT2, sj = inv_j * SQRT2;
    int pi = __builtin_amdgcn_cvt_pk_fp8_f32(a.x*si, a.y*si, 0, false);
    pi     = __builtin_amdgcn_cvt_pk_fp8_f32(a.z*si, a.w*si, pi, true);
    int pj = __builtin_amdgcn_cvt_pk_fp8_f32(b.x*sj, b.y*sj, 0, false);
    pj     = __builtin_amdgcn_cvt_pk_fp8_f32(b.z*sj, b.w*sj, pj, true);
    z8[(size_t)k * 64 + lane]        = pi;
    z8[(size_t)(k + BB) * 64 + lane] = pj;
    if (lane == 0) pos[k] = dot * inv_i * inv_j * 2.0f;
}

// Kernel B: partial[split][r] = sum over this split's 256 columns c of exp(z_r . z_c).
// MX-fp8 MFMA (16x16x128, unit scales) at 2x bf16 rate. 4 waves x 64 rows = 256
// rows/block; A register-resident (64 VGPRs). B-tiles (64 cols x 256 B = 16 KB)
// double-buffered via global_load_lds DMA issued one tile ahead.
// LDS swizzle: 16-B granule g of row r stored at physical granule g ^ (r&15) ->
// each ds_read_b128 spreads 8 lanes per 16-B bank-position (minimum phases).
__global__ __launch_bounds__(256, 2) void sim_kernel(const unsigned char* __restrict__ z8,
                                                     float* __restrict__ partial) {
    __shared__ unsigned char tb[2][CT * D];   // 2 x 16 KB
    const int tid = threadIdx.x;
    const int wid = tid >> 6, lane = tid & 63;
    const int lrow = lane & 15, quad = lane >> 4;
    const int r0 = blockIdx.x * 256 + wid * 64;       // this wave's 64 rows
    const int cbase = blockIdx.y * (R2 / NSPLIT);

    // DMA source mapping (fixed per thread): round i stages row r = i*16 + (tid>>4),
    // physical granule p = tid&15 (forced: dest = base + lane*16) <- logical granule
    // g = p ^ (r&15) = p ^ (tid>>4).
    const int srow = tid >> 4;
    const unsigned char* gstage = z8 + (size_t)(cbase + srow) * D + ((tid & 15) ^ srow) * 16;

    // Issue tile-0 DMA first so it overlaps the afrag global loads.
#pragma unroll
    for (int i = 0; i < 4; ++i)
        async16(gstage + i * 16 * D, &tb[0][i * 4096 + wid * 1024]);

    // A fragments: 64 rows x K=256 in registers. Lane layout (16x16x128 f8f6f4):
    // row = lane&15, k = (lane>>4)*32 + byte (linear over 8 VGPRs).
    i32x8 afrag[4][2];
#pragma unroll
    for (int m = 0; m < 4; ++m)
#pragma unroll
        for (int ks = 0; ks < 2; ++ks)
            afrag[m][ks] = *reinterpret_cast<const i32x8*>(
                z8 + (size_t)(r0 + m*16 + lrow) * D + ks*128 + quad*32);

    float racc[4][4];
#pragma unroll
    for (int m = 0; m < 4; ++m)
#pragma unroll
        for (int j = 0; j < 4; ++j) racc[m][j] = 0.f;

    __syncthreads();   // tile-0 DMA + afrag loads drained (vmcnt(0) before barrier)

    for (int ct = 0; ct < NT; ++ct) {
        const unsigned char* tbb = tb[ct & 1];
        if (ct + 1 < NT) {
            const unsigned char* gs = gstage + (size_t)(ct + 1) * (CT * D);
            unsigned char* dn = tb[(ct + 1) & 1];
#pragma unroll
            for (int i = 0; i < 4; ++i)
                async16(gs + i * 16 * D, dn + i * 4096 + wid * 1024);
        }
#pragma unroll
        for (int n = 0; n < 4; ++n) {
            const int rb = (n*16 + lrow) * D;
            i32x8 bfrag[2];
#pragma unroll
            for (int ks = 0; ks < 2; ++ks) {
                const int pe = (ks*8 + quad*2) ^ lrow;    // even-half physical granule
                i32x4 lo = *reinterpret_cast<const i32x4*>(&tbb[rb + pe * 16]);
                i32x4 hi = *reinterpret_cast<const i32x4*>(&tbb[rb + (pe ^ 1) * 16]);
                bfrag[ks][0] = lo[0]; bfrag[ks][1] = lo[1];
                bfrag[ks][2] = lo[2]; bfrag[ks][3] = lo[3];
                bfrag[ks][4] = hi[0]; bfrag[ks][5] = hi[1];
                bfrag[ks][6] = hi[2]; bfrag[ks][7] = hi[3];
            }
#pragma unroll
            for (int m = 0; m < 4; ++m) {
                f32x4 c = {0.f, 0.f, 0.f, 0.f};
                c = __builtin_amdgcn_mfma_scale_f32_16x16x128_f8f6f4(
                        afrag[m][0], bfrag[0], c, 0, 0, 0, 127, 0, 127);
                c = __builtin_amdgcn_mfma_scale_f32_16x16x128_f8f6f4(
                        afrag[m][1], bfrag[1], c, 0, 0, 0, 127, 0, 127);
#pragma unroll
                for (int j = 0; j < 4; ++j)
                    racc[m][j] += __expf(c[j]);
            }
        }
        __syncthreads();   // next tile's DMA drained; all waves done reading tbb
    }

    // Row sums: reduce over lane bits 0-3 (the col index); row = quad*4 + j.
#pragma unroll
    for (int m = 0; m < 4; ++m)
#pragma unroll
        for (int j = 0; j < 4; ++j) {
            float v = racc[m][j];
            v += __shfl_xor(v, 1);
            v += __shfl_xor(v, 2);
            v += __shfl_xor(v, 4);
            v += __shfl_xor(v, 8);
            if (lrow == 0)
                partial[(size_t)blockIdx.y * R2 + r0 + m*16 + quad*4 + j] = v;
        }
}

// Kernel C: loss_r = log(exp(p_r) + S_r - e^2) - p_r ; atomicAdd(out, blocksum/R2).
// 32 blocks x 256 threads (256 rows each); out zero-initialized by norm_kernel.
__global__ __launch_bounds__(256) void reduce_kernel(const float* __restrict__ partial,
                                                     const float* __restrict__ pos,
                                                     float* __restrict__ out) {
    __shared__ float wsum[4];
    const int tid = threadIdx.x;
    const int r = blockIdx.x * 256 + tid;
    float S = 0.f;
#pragma unroll
    for (int s = 0; s < NSPLIT; ++s) S += partial[(size_t)s * R2 + r];
    const float p = pos[r & (BB - 1)];
    float lsum = __logf(__expf(p) + S - E2) - p;
#pragma unroll
    for (int off = 32; off; off >>= 1) lsum += __shfl_xor(lsum, off);
    if ((tid & 63) == 0) wsum[tid >> 6] = lsum;
    __syncthreads();
    if (tid == 0) {
        float t = wsum[0] + wsum[1] + wsum[2] + wsum[3];
        atomicAdd(out, t * (1.0f / (float)R2));
    }
}

extern "C" void kernel_launch(void* const* d_in, const int* in_sizes, int n_in,
                              void* d_out, int out_size, void* d_ws, size_t ws_size,
                              hipStream_t stream) {
    (void)in_sizes; (void)n_in; (void)out_size; (void)ws_size;
    const float* xi = (const float*)d_in[0];
    const float* xj = (const float*)d_in[1];
    float* out = (float*)d_out;

    unsigned char* z8 = (unsigned char*)d_ws;                                  // 8192*256 = 2 MB
    float* partial = (float*)((char*)d_ws + (size_t)R2 * D);                   // 32*8192*4 = 1 MB
    float* pos     = (float*)((char*)d_ws + (size_t)R2 * D + (size_t)NSPLIT*R2*4);  // 16 KB

    norm_kernel<<<BB / 4, 256, 0, stream>>>(xi, xj, (int*)z8, pos, out);
    sim_kernel<<<dim3(R2 / 256, NSPLIT), 256, 0, stream>>>(z8, partial);
    reduce_kernel<<<NSPLIT, 256, 0, stream>>>(partial, pos, out);
}